// Round 3
// baseline (3220.950 us; speedup 1.0000x reference)
//
#include <hip/hip_runtime.h>
#include <hip/hip_bf16.h>

#define Sn    2048
#define HIDn  2048
#define HQn   16
#define HKVn  2
#define HDn   128
#define Gn    8
#define CSn   128
#define Ncn   16
#define NBLK  8
#define WINn  16
#define SCALEf 0.08838834764831845f   // 128^-0.5
#define NEGf  (-1.0e9f)
#define ALPHAf 0.8f
#define MIXLf  0.5f

// ---------------- fp32 GEMM: C[M,N] = A[M,K] @ W[K,N] + bias ----------------
// 64x64 tile, 256 threads, 4x4 per thread, K-step 16.
__global__ void gemm64(const float* __restrict__ A, const float* __restrict__ W,
                       const float* __restrict__ bias, float* __restrict__ C,
                       int M, int N, int K) {
    __shared__ float As[16][65];   // [kk][m], +1 pad
    __shared__ float Bs[16][65];   // [kk][n]
    const int tid = threadIdx.x;
    const int tx = tid & 15, ty = tid >> 4;
    const int m0 = blockIdx.y * 64, n0 = blockIdx.x * 64;
    float acc[4][4] = {};
    for (int k0 = 0; k0 < K; k0 += 16) {
#pragma unroll
        for (int r = 0; r < 4; ++r) {
            int flat = tid + 256 * r;
            int am = flat >> 4, ak = flat & 15;          // A: coalesced over k
            As[ak][am] = A[(size_t)(m0 + am) * K + k0 + ak];
            int bk = flat >> 6, bn = flat & 63;          // B: coalesced over n
            Bs[bk][bn] = W[(size_t)(k0 + bk) * N + n0 + bn];
        }
        __syncthreads();
#pragma unroll
        for (int kk = 0; kk < 16; ++kk) {
            float a[4], b[4];
#pragma unroll
            for (int i = 0; i < 4; ++i) a[i] = As[kk][ty * 4 + i];
#pragma unroll
            for (int j = 0; j < 4; ++j) b[j] = Bs[kk][tx * 4 + j];
#pragma unroll
            for (int i = 0; i < 4; ++i)
#pragma unroll
                for (int j = 0; j < 4; ++j) acc[i][j] += a[i] * b[j];
        }
        __syncthreads();
    }
#pragma unroll
    for (int i = 0; i < 4; ++i)
#pragma unroll
        for (int j = 0; j < 4; ++j) {
            int m = m0 + ty * 4 + i, n = n0 + tx * 4 + j;
            C[(size_t)m * N + n] = acc[i][j] + (bias ? bias[n] : 0.0f);
        }
}

// ---------------- RoPE in-place on q [S,16,128] and k [S,2,128] ----------------
__global__ void rope_kernel(float* __restrict__ q, float* __restrict__ k,
                            const float* __restrict__ cosb, const float* __restrict__ sinb) {
    int idx = blockIdx.x * blockDim.x + threadIdx.x;   // S*18*64 total
    int s = idx / (18 * 64);
    int r = idx % (18 * 64);
    int head = r >> 6;
    int d = r & 63;
    float* base = (head < 16) ? (q + (size_t)s * 2048 + head * 128)
                              : (k + (size_t)s * 256 + (head - 16) * 128);
    float c0 = cosb[s * 128 + d], c1 = cosb[s * 128 + d + 64];
    float s0 = sinb[s * 128 + d], s1 = sinb[s * 128 + d + 64];
    float x0 = base[d], x1 = base[d + 64];
    base[d]      = x0 * c0 - x1 * s0;   // q*cos + rotate_half(q)*sin, low half
    base[d + 64] = x1 * c1 + x0 * s1;   // high half
}

// ---------------- per-chunk K stats: mean & max over 128 positions ----------------
__global__ void chunk_stats(const float* __restrict__ k, float* __restrict__ kcm,
                            float* __restrict__ kcx) {
    int c = blockIdx.x & 15, kv = blockIdx.x >> 4;
    int d = threadIdx.x;   // 128
    float sum = 0.f, mx = -INFINITY;
    for (int j = 0; j < 128; ++j) {
        float v = k[(size_t)(c * 128 + j) * 256 + kv * 128 + d];
        sum += v; mx = fmaxf(mx, v);
    }
    kcm[(kv * 16 + c) * 128 + d] = sum * (1.0f / 128.0f);
    kcx[(kv * 16 + c) * 128 + d] = mx;
}

// ---------------- block scores + top-8 selection -> 16-bit chunk mask ----------------
__global__ void block_scores(const float* __restrict__ q, const float* __restrict__ kcm,
                             const float* __restrict__ kcx, unsigned int* __restrict__ mask32) {
    int qpos = blockIdx.x, kv = blockIdx.y;
    int t = threadIdx.x;          // 128: t = c*8 + g
    int c = t >> 3, g = t & 7;
    int h = kv * 8 + g;
    const float* qr = q + (size_t)qpos * 2048 + h * 128;
    const float* km = kcm + (kv * 16 + c) * 128;
    const float* kx = kcx + (kv * 16 + c) * 128;
    float dm = 0.f, dx = 0.f;
#pragma unroll 4
    for (int d = 0; d < 128; ++d) { float qv = qr[d]; dm += qv * km[d]; dx += qv * kx[d]; }
    float sg = (MIXLf * dm + (1.0f - MIXLf) * dx) * SCALEf;
    __shared__ float sh[16][8];
    __shared__ float vals[16];
    sh[c][g] = sg;
    __syncthreads();
    if (t < 16) {
        float mean = 0.f, mxv = -INFINITY;
#pragma unroll
        for (int gg = 0; gg < 8; ++gg) { mean += sh[t][gg]; mxv = fmaxf(mxv, sh[t][gg]); }
        mean *= 0.125f;
        float v = ALPHAf * mean + (1.0f - ALPHAf) * mxv;
        if (t * 128 > qpos) v = NEGf;      // causal_blk pre-filter (as in reference)
        vals[t] = v;
    }
    __syncthreads();
    if (t == 0) {
        unsigned int bits = 0;
        bool taken[16] = {};
        for (int it = 0; it < NBLK; ++it) {      // top-8, ties -> lowest index (lax.top_k)
            int best = 0; float bv = -INFINITY;
            for (int cc = 0; cc < 16; ++cc)
                if (!taken[cc] && vals[cc] > bv) { bv = vals[cc]; best = cc; }
            taken[best] = true;
            bits |= (1u << best);
        }
        int lastc = qpos >> 7;
        unsigned int causal_bits = (1u << (lastc + 1)) - 1u;
        mask32[kv * 2048 + qpos] = bits & causal_bits;
    }
}

// ---------------- sparse attention, one block (128 thr) per (qpos, head) ----------------
// Writes output in-place into q (each block reads/writes only its own row segment).
__global__ void sparse_attn(float* __restrict__ q, const float* __restrict__ k,
                            const float* __restrict__ v, const unsigned int* __restrict__ mask32,
                            const int* __restrict__ am) {
    int qpos = blockIdx.x;
    int h = blockIdx.y;
    int kv = h >> 3;
    int t = threadIdx.x;   // 128
    __shared__ float q_sh[128];
    __shared__ float red[128];
    __shared__ float p_sh[128];
    float* qrow = q + (size_t)qpos * 2048 + h * 128;
    q_sh[t] = qrow[t];
    __syncthreads();
    unsigned int bits = mask32[kv * 2048 + qpos];
    int lastc = qpos >> 7;
    float m_run = -INFINITY, l_run = 0.f, o = 0.f;
    for (int c = 0; c <= lastc; ++c) {
        bool selected = (bits >> c) & 1u;
        bool wover = (c * 128 + 127) >= (qpos - (WINn - 1));   // window overlaps chunk
        if (!selected && !wover) continue;                     // chunk-uniform branch
        int kpos = c * 128 + t;
        bool allowed = (kpos <= qpos) && (selected || (qpos - kpos) < WINn) && (am[kpos] != 0);
        float logit = NEGf;
        if (allowed) {
            const float* krow = k + (size_t)kpos * 256 + kv * 128;
            float dot = 0.f;
#pragma unroll 8
            for (int d = 0; d < 128; ++d) dot += q_sh[d] * krow[d];
            logit = dot * SCALEf;
        }
        red[t] = logit; __syncthreads();
        for (int sft = 64; sft > 0; sft >>= 1) {
            if (t < sft) red[t] = fmaxf(red[t], red[t + sft]);
            __syncthreads();
        }
        float cmax = red[0]; __syncthreads();
        float newm = fmaxf(m_run, cmax);
        float p = __expf(logit - newm);
        p_sh[t] = p;
        red[t] = p; __syncthreads();
        for (int sft = 64; sft > 0; sft >>= 1) {
            if (t < sft) red[t] += red[t + sft];
            __syncthreads();
        }
        float csum = red[0]; __syncthreads();
        float factor = __expf(m_run - newm);   // exp(-inf)=0 on first active chunk
        l_run = l_run * factor + csum;
        float oacc = 0.f;
        const float* vbase = v + (size_t)c * 128 * 256 + kv * 128 + t;   // t = dim d
#pragma unroll 4
        for (int j = 0; j < 128; ++j) oacc += p_sh[j] * vbase[(size_t)j * 256];
        o = o * factor + oacc;
        m_run = newm;
        __syncthreads();   // protect p_sh/red for next chunk
    }
    qrow[t] = o / l_run;
}

extern "C" void kernel_launch(void* const* d_in, const int* in_sizes, int n_in,
                              void* d_out, int out_size, void* d_ws, size_t ws_size,
                              hipStream_t stream) {
    const float* hs   = (const float*)d_in[0];
    const float* cosb = (const float*)d_in[1];
    const float* sinb = (const float*)d_in[2];
    const int*   am   = (const int*)d_in[3];
    // d_in[4] = input_length (unused)
    const float* Wq = (const float*)d_in[5];
    const float* bq = (const float*)d_in[6];
    const float* Wk = (const float*)d_in[7];
    const float* bk = (const float*)d_in[8];
    const float* Wv = (const float*)d_in[9];
    const float* bv = (const float*)d_in[10];
    const float* Wo = (const float*)d_in[11];
    float* out = (float*)d_out;

    float* qbuf = (float*)d_ws;                       // [2048, 16, 128]
    float* kbuf = qbuf + (size_t)Sn * HIDn;           // [2048, 2, 128]
    float* vbuf = kbuf + (size_t)Sn * HKVn * HDn;     // [2048, 2, 128]
    float* kcm  = vbuf + (size_t)Sn * HKVn * HDn;     // [2, 16, 128]
    float* kcx  = kcm + HKVn * Ncn * HDn;
    unsigned int* mask32 = (unsigned int*)(kcx + HKVn * Ncn * HDn);   // [2, 2048]

    dim3 blk(256);
    gemm64<<<dim3(HIDn / 64, Sn / 64), blk, 0, stream>>>(hs, Wq, bq, qbuf, Sn, HIDn, HIDn);
    gemm64<<<dim3((HKVn * HDn) / 64, Sn / 64), blk, 0, stream>>>(hs, Wk, bk, kbuf, Sn, HKVn * HDn, HIDn);
    gemm64<<<dim3((HKVn * HDn) / 64, Sn / 64), blk, 0, stream>>>(hs, Wv, bv, vbuf, Sn, HKVn * HDn, HIDn);
    rope_kernel<<<(Sn * 18 * 64) / 256, 256, 0, stream>>>(qbuf, kbuf, cosb, sinb);
    chunk_stats<<<HKVn * Ncn, 128, 0, stream>>>(kbuf, kcm, kcx);
    block_scores<<<dim3(Sn, HKVn), 128, 0, stream>>>(qbuf, kcm, kcx, mask32);
    sparse_attn<<<dim3(Sn, HQn), 128, 0, stream>>>(qbuf, kbuf, vbuf, mask32, am);
    gemm64<<<dim3(HIDn / 64, Sn / 64), blk, 0, stream>>>(qbuf, Wo, nullptr, out, Sn, HIDn, HIDn);
}

// Round 4
// 1583.045 us; speedup vs baseline: 2.0347x; 2.0347x over previous
//
#include <hip/hip_runtime.h>
#include <hip/hip_bf16.h>

#define Sn    2048
#define HIDn  2048
#define HQn   16
#define HKVn  2
#define HDn   128
#define Gn    8
#define CSn   128
#define Ncn   16
#define NBLK  8
#define WINn  16
#define SCALEf 0.08838834764831845f   // 128^-0.5
#define NEGf  (-1.0e9f)
#define ALPHAf 0.8f
#define MIXLf  0.5f

typedef __attribute__((ext_vector_type(8))) short short8;   // 8 bf16 = 4 VGPRs
typedef __attribute__((ext_vector_type(4))) float f32x4;

// float -> bf16 bits, round-nearest-even (inputs finite)
static __device__ __forceinline__ short f2bf(float x) {
    union { float f; unsigned u; } v; v.f = x;
    unsigned r = v.u + 0x7fffu + ((v.u >> 16) & 1u);
    return (short)(r >> 16);
}

// ---------------- fp32 GEMM: C[M,N] = A[M,K] @ W[K,N] + bias ----------------
__global__ void gemm64(const float* __restrict__ A, const float* __restrict__ W,
                       const float* __restrict__ bias, float* __restrict__ C,
                       int M, int N, int K) {
    __shared__ float As[16][65];
    __shared__ float Bs[16][65];
    const int tid = threadIdx.x;
    const int tx = tid & 15, ty = tid >> 4;
    const int m0 = blockIdx.y * 64, n0 = blockIdx.x * 64;
    float acc[4][4] = {};
    for (int k0 = 0; k0 < K; k0 += 16) {
#pragma unroll
        for (int r = 0; r < 4; ++r) {
            int flat = tid + 256 * r;
            int am = flat >> 4, ak = flat & 15;
            As[ak][am] = A[(size_t)(m0 + am) * K + k0 + ak];
            int bk = flat >> 6, bn = flat & 63;
            Bs[bk][bn] = W[(size_t)(k0 + bk) * N + n0 + bn];
        }
        __syncthreads();
#pragma unroll
        for (int kk = 0; kk < 16; ++kk) {
            float a[4], b[4];
#pragma unroll
            for (int i = 0; i < 4; ++i) a[i] = As[kk][ty * 4 + i];
#pragma unroll
            for (int j = 0; j < 4; ++j) b[j] = Bs[kk][tx * 4 + j];
#pragma unroll
            for (int i = 0; i < 4; ++i)
#pragma unroll
                for (int j = 0; j < 4; ++j) acc[i][j] += a[i] * b[j];
        }
        __syncthreads();
    }
#pragma unroll
    for (int i = 0; i < 4; ++i)
#pragma unroll
        for (int j = 0; j < 4; ++j) {
            int m = m0 + ty * 4 + i, n = n0 + tx * 4 + j;
            C[(size_t)m * N + n] = acc[i][j] + (bias ? bias[n] : 0.0f);
        }
}

// ---------------- RoPE in-place + bf16 emission ----------------
// qb: [s][16][128] bf16 bits; kb: [kv][s][128] bf16 bits
__global__ void rope_kernel(float* __restrict__ q, float* __restrict__ k,
                            const float* __restrict__ cosb, const float* __restrict__ sinb,
                            short* __restrict__ qb, short* __restrict__ kb) {
    int idx = blockIdx.x * blockDim.x + threadIdx.x;   // S*18*64
    int s = idx / (18 * 64);
    int r = idx % (18 * 64);
    int head = r >> 6;
    int d = r & 63;
    float c0 = cosb[s * 128 + d], c1 = cosb[s * 128 + d + 64];
    float s0 = sinb[s * 128 + d], s1 = sinb[s * 128 + d + 64];
    if (head < 16) {
        float* base = q + (size_t)s * 2048 + head * 128;
        float x0 = base[d], x1 = base[d + 64];
        float y0 = x0 * c0 - x1 * s0;
        float y1 = x1 * c1 + x0 * s1;
        base[d] = y0; base[d + 64] = y1;
        short* qo = qb + ((size_t)s * 16 + head) * 128;
        qo[d] = f2bf(y0); qo[d + 64] = f2bf(y1);
    } else {
        int kv = head - 16;
        float* base = k + (size_t)s * 256 + kv * 128;
        float x0 = base[d], x1 = base[d + 64];
        float y0 = x0 * c0 - x1 * s0;
        float y1 = x1 * c1 + x0 * s1;
        base[d] = y0; base[d + 64] = y1;
        short* ko = kb + ((size_t)kv * Sn + s) * 128;
        ko[d] = f2bf(y0); ko[d + 64] = f2bf(y1);
    }
}

// ---------------- V -> bf16, transposed per chunk: vtb[kv][c][d][j] ----------------
__global__ void conv_v(const float* __restrict__ v, short* __restrict__ vtb) {
    int idx = blockIdx.x * blockDim.x + threadIdx.x;   // S*256
    int pos = idx >> 8;
    int rem = idx & 255;
    int kv = rem >> 7, d = rem & 127;
    float val = v[(size_t)pos * 256 + kv * 128 + d];
    int c = pos >> 7, j = pos & 127;
    vtb[(((size_t)kv * Ncn + c) * 128 + d) * 128 + j] = f2bf(val);
}

// ---------------- per-chunk K stats ----------------
__global__ void chunk_stats(const float* __restrict__ k, float* __restrict__ kcm,
                            float* __restrict__ kcx) {
    int c = blockIdx.x & 15, kv = blockIdx.x >> 4;
    int d = threadIdx.x;
    float sum = 0.f, mx = -INFINITY;
    for (int j = 0; j < 128; ++j) {
        float v = k[(size_t)(c * 128 + j) * 256 + kv * 128 + d];
        sum += v; mx = fmaxf(mx, v);
    }
    kcm[(kv * 16 + c) * 128 + d] = sum * (1.0f / 128.0f);
    kcx[(kv * 16 + c) * 128 + d] = mx;
}

// ---------------- block scores + top-8 -> 16-bit chunk mask (fp32, matches ref) ----
__global__ void block_scores(const float* __restrict__ q, const float* __restrict__ kcm,
                             const float* __restrict__ kcx, unsigned int* __restrict__ mask32) {
    int qpos = blockIdx.x, kv = blockIdx.y;
    int t = threadIdx.x;          // 128: t = c*8 + g
    int c = t >> 3, g = t & 7;
    int h = kv * 8 + g;
    const float* qr = q + (size_t)qpos * 2048 + h * 128;
    const float* km = kcm + (kv * 16 + c) * 128;
    const float* kx = kcx + (kv * 16 + c) * 128;
    float dm = 0.f, dx = 0.f;
#pragma unroll 4
    for (int d = 0; d < 128; ++d) { float qv = qr[d]; dm += qv * km[d]; dx += qv * kx[d]; }
    float sg = (MIXLf * dm + (1.0f - MIXLf) * dx) * SCALEf;
    __shared__ float sh[16][8];
    __shared__ float vals[16];
    sh[c][g] = sg;
    __syncthreads();
    if (t < 16) {
        float mean = 0.f, mxv = -INFINITY;
#pragma unroll
        for (int gg = 0; gg < 8; ++gg) { mean += sh[t][gg]; mxv = fmaxf(mxv, sh[t][gg]); }
        mean *= 0.125f;
        float v = ALPHAf * mean + (1.0f - ALPHAf) * mxv;
        if (t * 128 > qpos) v = NEGf;
        vals[t] = v;
    }
    __syncthreads();
    if (t == 0) {
        unsigned int bits = 0;
        bool taken[16] = {};
        for (int it = 0; it < NBLK; ++it) {
            int best = 0; float bv = -INFINITY;
            for (int cc = 0; cc < 16; ++cc)
                if (!taken[cc] && vals[cc] > bv) { bv = vals[cc]; best = cc; }
            taken[best] = true;
            bits |= (1u << best);
        }
        int lastc = qpos >> 7;
        unsigned int causal_bits = (1u << (lastc + 1)) - 1u;
        mask32[kv * 2048 + qpos] = bits & causal_bits;
    }
}

// ---------------- MFMA flash attention ----------------
// Grid (32, 16): blockIdx.x = 64-row q-tile, blockIdx.y = head. 256 thr = 4 waves,
// each wave owns a 16-row strip. mfma_f32_16x16x32_bf16:
//   A-frag: A[m=lane&15][k=quad*8+j]   B-frag: B^T[n=lane&15][k=quad*8+j]
//   C/D:    col=lane&15, row=quad*4+reg          (m89/m120-verified)
__global__ __launch_bounds__(256) void attn_mfma(
        const short* __restrict__ qb, const short* __restrict__ kb,
        const short* __restrict__ vtb, const unsigned int* __restrict__ mask32,
        const int* __restrict__ am, float* __restrict__ qbuf) {
    __shared__ short Psh[4][16][136];   // per-wave P strip, +8 pad (2-way = free)
    const int tid = threadIdx.x;
    const int w = tid >> 6, lane = tid & 63;
    const int n = lane & 15, quad = lane >> 4;
    const int h = blockIdx.y, kv = h >> 3;
    const int r0 = (blockIdx.x * 4 + w) * 16;

    int qpos[4];
    unsigned rb[4];
#pragma unroll
    for (int r = 0; r < 4; ++r) {
        qpos[r] = r0 + quad * 4 + r;
        rb[r] = mask32[kv * Sn + qpos[r]];
    }
    // union of 16 rows' chunk bits
    unsigned bits = (lane < 16) ? mask32[kv * Sn + r0 + lane] : 0u;
#pragma unroll
    for (int off = 1; off < 64; off <<= 1) bits |= __shfl_xor(bits, off, 64);
    int wl = (r0 >= 15) ? ((r0 - 15) >> 7) : 0;
    int wh = (r0 + 15) >> 7;
    for (int c = wl; c <= wh; ++c) bits |= (1u << c);
    const int cm = (r0 + 15) >> 7;
    bits &= (1u << (cm + 1)) - 1u;

    // Q fragments (persist all kernel)
    short8 qf[4];
    const short* qrow = qb + ((size_t)(r0 + n) * 16 + h) * 128;
#pragma unroll
    for (int ks = 0; ks < 4; ++ks) qf[ks] = *(const short8*)(qrow + ks * 32 + quad * 8);

    f32x4 oacc[8];
#pragma unroll
    for (int dt = 0; dt < 8; ++dt) oacc[dt] = (f32x4){0.f, 0.f, 0.f, 0.f};
    float m[4] = {-INFINITY, -INFINITY, -INFINITY, -INFINITY};
    float l[4] = {0.f, 0.f, 0.f, 0.f};

    for (int c = 0; c <= cm; ++c) {
        if (!((bits >> c) & 1u)) continue;
        // ---- S = Q K^T over this 128-key chunk (8 16-col tiles) ----
        f32x4 sacc[8];
        const short* kcbase = kb + ((size_t)kv * Sn + c * 128) * 128;
#pragma unroll
        for (int t = 0; t < 8; ++t) {
            const short* krow = kcbase + (t * 16 + n) * 128;
            f32x4 a = (f32x4){0.f, 0.f, 0.f, 0.f};
#pragma unroll
            for (int ks = 0; ks < 4; ++ks) {
                short8 kf = *(const short8*)(krow + ks * 32 + quad * 8);
                a = __builtin_amdgcn_mfma_f32_16x16x32_bf16(qf[ks], kf, a, 0, 0, 0);
            }
            sacc[t] = a;
        }
        // ---- mask + row max ----
        float cmax[4] = {-INFINITY, -INFINITY, -INFINITY, -INFINITY};
#pragma unroll
        for (int t = 0; t < 8; ++t) {
            int kp = c * 128 + t * 16 + n;
            bool amv = am[kp] != 0;
#pragma unroll
            for (int r = 0; r < 4; ++r) {
                float s = sacc[t][r] * SCALEf;
                bool ok = (kp <= qpos[r]) && amv &&
                          (((rb[r] >> c) & 1u) || (qpos[r] - kp) < WINn);
                s = ok ? s : NEGf;
                sacc[t][r] = s;
                cmax[r] = fmaxf(cmax[r], s);
            }
        }
#pragma unroll
        for (int r = 0; r < 4; ++r)
#pragma unroll
            for (int off = 1; off < 16; off <<= 1)
                cmax[r] = fmaxf(cmax[r], __shfl_xor(cmax[r], off, 64));
        float fac[4], rsum[4];
#pragma unroll
        for (int r = 0; r < 4; ++r) {
            float newm = fmaxf(m[r], cmax[r]);
            fac[r] = __expf(m[r] - newm);
            m[r] = newm;
            rsum[r] = 0.f;
        }
        // ---- P = exp(S - m); write to LDS strip (C-layout -> A-layout) ----
#pragma unroll
        for (int t = 0; t < 8; ++t)
#pragma unroll
            for (int r = 0; r < 4; ++r) {
                float p = __expf(sacc[t][r] - m[r]);
                rsum[r] += p;
                Psh[w][quad * 4 + r][t * 16 + n] = f2bf(p);
            }
#pragma unroll
        for (int r = 0; r < 4; ++r) {
#pragma unroll
            for (int off = 1; off < 16; off <<= 1)
                rsum[r] += __shfl_xor(rsum[r], off, 64);
            l[r] = l[r] * fac[r] + rsum[r];
        }
#pragma unroll
        for (int dt = 0; dt < 8; ++dt)
#pragma unroll
            for (int r = 0; r < 4; ++r) oacc[dt][r] *= fac[r];
        // ---- O += P V ----
        short8 pf[4];
        const short* prow = &Psh[w][n][0];
#pragma unroll
        for (int ks = 0; ks < 4; ++ks) pf[ks] = *(const short8*)(prow + ks * 32 + quad * 8);
        const short* vcbase = vtb + (((size_t)kv * Ncn + c) * 128) * 128;
#pragma unroll
        for (int dt = 0; dt < 8; ++dt) {
            const short* vrow = vcbase + (dt * 16 + n) * 128;
#pragma unroll
            for (int ks = 0; ks < 4; ++ks) {
                short8 vf = *(const short8*)(vrow + ks * 32 + quad * 8);
                oacc[dt] = __builtin_amdgcn_mfma_f32_16x16x32_bf16(pf[ks], vf, oacc[dt], 0, 0, 0);
            }
        }
    }
    float inv[4];
#pragma unroll
    for (int r = 0; r < 4; ++r) inv[r] = 1.0f / l[r];
#pragma unroll
    for (int dt = 0; dt < 8; ++dt)
#pragma unroll
        for (int r = 0; r < 4; ++r)
            qbuf[(size_t)qpos[r] * 2048 + h * 128 + dt * 16 + n] = oacc[dt][r] * inv[r];
}

extern "C" void kernel_launch(void* const* d_in, const int* in_sizes, int n_in,
                              void* d_out, int out_size, void* d_ws, size_t ws_size,
                              hipStream_t stream) {
    const float* hs   = (const float*)d_in[0];
    const float* cosb = (const float*)d_in[1];
    const float* sinb = (const float*)d_in[2];
    const int*   am   = (const int*)d_in[3];
    const float* Wq = (const float*)d_in[5];
    const float* bq = (const float*)d_in[6];
    const float* Wk = (const float*)d_in[7];
    const float* bk = (const float*)d_in[8];
    const float* Wv = (const float*)d_in[9];
    const float* bv = (const float*)d_in[10];
    const float* Wo = (const float*)d_in[11];
    float* out = (float*)d_out;

    float* qbuf = (float*)d_ws;                       // [2048,16,128] fp32
    float* kbuf = qbuf + (size_t)Sn * HIDn;           // [2048,2,128]
    float* vbuf = kbuf + (size_t)Sn * HKVn * HDn;     // [2048,2,128]
    float* kcm  = vbuf + (size_t)Sn * HKVn * HDn;     // [2,16,128]
    float* kcx  = kcm + HKVn * Ncn * HDn;
    unsigned int* mask32 = (unsigned int*)(kcx + HKVn * Ncn * HDn);  // [2,2048]
    short* qb  = (short*)(mask32 + HKVn * Sn);        // [2048,16,128] bf16
    short* kb  = qb + (size_t)Sn * HIDn;              // [2,2048,128] bf16
    short* vtb = kb + (size_t)HKVn * Sn * HDn;        // [2,16,128,128] bf16

    dim3 blk(256);
    gemm64<<<dim3(HIDn / 64, Sn / 64), blk, 0, stream>>>(hs, Wq, bq, qbuf, Sn, HIDn, HIDn);
    gemm64<<<dim3((HKVn * HDn) / 64, Sn / 64), blk, 0, stream>>>(hs, Wk, bk, kbuf, Sn, HKVn * HDn, HIDn);
    gemm64<<<dim3((HKVn * HDn) / 64, Sn / 64), blk, 0, stream>>>(hs, Wv, bv, vbuf, Sn, HKVn * HDn, HIDn);
    rope_kernel<<<(Sn * 18 * 64) / 256, 256, 0, stream>>>(qbuf, kbuf, cosb, sinb, qb, kb);
    conv_v<<<(Sn * 256) / 256, 256, 0, stream>>>(vbuf, vtb);
    chunk_stats<<<HKVn * Ncn, 128, 0, stream>>>(kbuf, kcm, kcx);
    block_scores<<<dim3(Sn, HKVn), 128, 0, stream>>>(qbuf, kcm, kcx, mask32);
    attn_mfma<<<dim3(Sn / 64, HQn), 256, 0, stream>>>(qb, kb, vtb, mask32, am, qbuf);
    gemm64<<<dim3(HIDn / 64, Sn / 64), blk, 0, stream>>>(qbuf, Wo, nullptr, out, Sn, HIDn, HIDn);
}